// Round 12
// baseline (546.230 us; speedup 1.0000x reference)
//
#include <hip/hip_runtime.h>
#include <hip/hip_bf16.h>
#include <hip/hip_cooperative_groups.h>
#include <stdint.h>

namespace cg = cooperative_groups;

// Problem constants (fixed by setup_inputs)
#define PRIME 2147483647u
#define GAMMA 0.3f
#define K_HASH 128
#define S_SET 8
#define NB 4
#define LQ 1024
#define LK 1024
#define EDIM 512

typedef unsigned short ushort_t;
typedef __attribute__((ext_vector_type(8))) short short8;
typedef __attribute__((ext_vector_type(4))) float f32x4;

static __device__ __forceinline__ unsigned short f2bf(float f) {
    unsigned u = __builtin_bit_cast(unsigned, f);
    u += 0x7FFFu + ((u >> 16) & 1u);   // RNE (no NaN in this problem)
    return (unsigned short)(u >> 16);
}

// async global->LDS, 16B per lane; LDS dst must be lane-contiguous.
static __device__ __forceinline__ void glds16(const void* g, void* l) {
    __builtin_amdgcn_global_load_lds(
        (const __attribute__((address_space(1))) unsigned int*)g,
        (__attribute__((address_space(3))) unsigned int*)l, 16, 0, 0);
}

#define SWZ(r) ((((r) >> 2) & 3) ^ ((r) & 3))

// score(m) = exp(exp(-GAMMA * 2S * (K-m)/(K+m))), m = matched hash slots
static __device__ __forceinline__ float score_of(int m) {
    float r = (float)(K_HASH - m) / (float)(K_HASH + m);
    return expf(expf(-GAMMA * (2.0f * S_SET) * r));
}

// ---------------------------------------------------------------------------
// Shared-memory union for all phases (max 35.4 KB -> 2 blocks/CU co-resident)
// ---------------------------------------------------------------------------
union FSmem {
    struct { unsigned tile[128 * 65]; int ids[64 * S_SET]; } t;   // 35.3 KB
    struct { unsigned keys[2048]; ushort_t vals[2048]; } j;       // 12 KB
    struct { ushort_t As[2][64 * 32]; ushort_t Bs[2][64 * 32]; } g; // 16 KB
    struct { unsigned lj[256]; float lp[256]; unsigned lcnt; } o;   // 2 KB
};

// ---------------------------------------------------------------------------
// 64x64-tile bf16 BT-GEMM device fn: C=A@B^T, f32 accum, 4 waves x 32x32,
// glds width-16, XOR-swizzled LDS, double-buffered.
// SEPI=1: atomicAdd per-column f32 sums into Sacc[b][n] (b = m0>>10).
// ---------------------------------------------------------------------------
template<int SEPI>
static __device__ void gemm64_dev(
        const ushort_t* __restrict__ A, const ushort_t* __restrict__ B,
        ushort_t* __restrict__ C, float* __restrict__ Sacc,
        int lda, int ldb, int ldc, int Kd, int m0, int n0,
        ushort_t* AsBase, ushort_t* BsBase, int tid) {
    ushort_t (*As)[64 * 32] = (ushort_t (*)[64 * 32])AsBase;
    ushort_t (*Bs)[64 * 32] = (ushort_t (*)[64 * 32])BsBase;
    int w = tid >> 6, lane = tid & 63;
    int wm = (w & 1) * 32, wn = (w >> 1) * 32;
    int mrow = lane & 15, kg = lane >> 4;

    int r = tid >> 2, c = (tid & 3) ^ SWZ(r);
    const ushort_t* pa = A + (size_t)(m0 + r) * lda + c * 8;
    const ushort_t* pb = B + (size_t)(n0 + r) * ldb + c * 8;

    int aoff[2], boff[2];
    #pragma unroll
    for (int s = 0; s < 2; s++) {
        int Ra = wm + s * 16 + mrow;
        aoff[s] = Ra * 32 + (kg ^ SWZ(Ra)) * 8;
        int Rb = wn + s * 16 + mrow;
        boff[s] = Rb * 32 + (kg ^ SWZ(Rb)) * 8;
    }

    f32x4 acc[2][2] = {};
    int nK = Kd >> 5;
    glds16(pa, &As[0][tid * 8]);
    glds16(pb, &Bs[0][tid * 8]);
    for (int i = 0; i < nK; i++) {
        __syncthreads();
        int cur = i & 1, nxt = cur ^ 1;
        if (i + 1 < nK) {
            int k0 = (i + 1) << 5;
            glds16(pa + k0, &As[nxt][tid * 8]);
            glds16(pb + k0, &Bs[nxt][tid * 8]);
        }
        short8 af[2], bh[2];
        #pragma unroll
        for (int s = 0; s < 2; s++) {
            af[s] = *(const short8*)&As[cur][aoff[s]];
            bh[s] = *(const short8*)&Bs[cur][boff[s]];
        }
        #pragma unroll
        for (int ii = 0; ii < 2; ii++)
            #pragma unroll
            for (int jj = 0; jj < 2; jj++)
                acc[ii][jj] = __builtin_amdgcn_mfma_f32_16x16x32_bf16(
                                  af[ii], bh[jj], acc[ii][jj], 0, 0, 0);
    }

    int col = lane & 15, rbase = (lane >> 4) * 4;
    #pragma unroll
    for (int ii = 0; ii < 2; ii++) {
        #pragma unroll
        for (int jj = 0; jj < 2; jj++) {
            #pragma unroll
            for (int rr = 0; rr < 4; rr++) {
                int gm = m0 + wm + ii * 16 + rbase + rr;
                int gn = n0 + wn + jj * 16 + col;
                C[(size_t)gm * ldc + gn] = f2bf(acc[ii][jj][rr]);
            }
        }
    }
    if (SEPI) {
        #pragma unroll
        for (int jj = 0; jj < 2; jj++) {
            float s = 0.f;
            #pragma unroll
            for (int ii = 0; ii < 2; ii++)
                #pragma unroll
                for (int rr = 0; rr < 4; rr++) s += acc[ii][jj][rr];
            s += __shfl_xor(s, 16);
            s += __shfl_xor(s, 32);
            if ((lane >> 4) == 0)
                atomicAdd(&Sacc[(m0 >> 10) * EDIM + n0 + wn + jj * 16 + col], s);
        }
    }
}

// ---------------------------------------------------------------------------
// Fused 4-phase pipeline, 512 blocks x 256 threads, grid.sync between phases.
// phase 0: sigT (128) | bob (8) | S zero (1) | WvT (64) | converts+Mzero (311)
// phase 1: Wvo = Wob@WvT^T (64) | sparse join (448 blocks, 512 (b,k) units)
// phase 2: W2c = Vb@Wvo^T (512 tiles) with column-sum S epilogue
// phase 3: out rows (8 per block)
// Launched cooperatively with (plo,phi)=(0,3); non-coop fallback launches the
// same kernel 4x with plo==phi (grid.sync never executed).
// ---------------------------------------------------------------------------
#define CVT_N0 (NB * LK * EDIM)
#define CVT_N1 (EDIM * EDIM)
#define CVT_U ((CVT_N0 + CVT_N1) / 8)       // 294912 convert units (8 f32 each)
#define MZ_U (NB * LQ * LK / 16)            // 262144 int4-zero units
#define TOT_U (CVT_U + MZ_U)                // 557056

__global__ __launch_bounds__(256, 2) void fused_kernel(
        const float* __restrict__ value, const float* __restrict__ Wv,
        const float* __restrict__ Wo, const float* __restrict__ bv,
        const float* __restrict__ bo,
        const int* __restrict__ ts_q, const int* __restrict__ ts_k,
        const int* __restrict__ ha, const int* __restrict__ hb,
        unsigned* __restrict__ sigTq, unsigned* __restrict__ sigTk,
        uint8_t* __restrict__ M,
        ushort_t* __restrict__ Vb, ushort_t* __restrict__ Wob,
        ushort_t* __restrict__ WvT, ushort_t* __restrict__ Wvo,
        ushort_t* __restrict__ W2c, float* __restrict__ S,
        float* __restrict__ bob, float* __restrict__ out,
        int plo, int phi) {
    __shared__ FSmem sm;
    int blk = blockIdx.x, tid = threadIdx.x;

    for (int ph = plo; ph <= phi; ph++) {
        if (ph == 0) {
            if (blk < 128) {
                // ---- sigT: 64 rows x all 128 k, written column-major ----
                int r0 = blk * 64;        // global row 0..8191 (q then k)
                const int* ts = (r0 < NB * LQ) ? ts_q : ts_k;
                unsigned* sigT = (r0 < NB * LQ) ? sigTq : sigTk;
                int base = r0 & (NB * LQ - 1);
                ((int2*)sm.t.ids)[tid] =
                    ((const int2*)(ts + (size_t)base * S_SET))[tid];
                __syncthreads();
                int kt = tid & 127, rt = tid >> 7;
                unsigned long long a  = (unsigned)ha[kt];
                unsigned long long bb = (unsigned)hb[kt];
                for (int r = rt; r < 64; r += 2) {
                    unsigned mn = 0xFFFFFFFFu;
                    #pragma unroll
                    for (int s = 0; s < S_SET; s++) {
                        unsigned long long x =
                            a * (unsigned long long)(unsigned)sm.t.ids[r * S_SET + s] + bb;
                        x = (x & PRIME) + (x >> 31);   // 2^31 == 1 (mod 2^31-1)
                        x = (x & PRIME) + (x >> 31);
                        unsigned rr = (unsigned)x;
                        if (rr >= PRIME) rr -= PRIME;
                        mn = (rr < mn) ? rr : mn;
                    }
                    sm.t.tile[kt * 65 + r] = mn;
                }
                __syncthreads();
                #pragma unroll
                for (int ch = 0; ch < 32; ch++) {
                    int idx = ch * 256 + tid;
                    int k = idx >> 6, r = idx & 63;
                    sigT[(size_t)k * (NB * LQ) + base + r] = sm.t.tile[k * 65 + r];
                }
            } else if (blk < 136) {
                // ---- bob = bo + bv@Wo^T: wave-per-row coalesced reduce ----
                int w = tid >> 6, lane = tid & 63;
                #pragma unroll
                for (int i = 0; i < 16; i++) {
                    int row = (blk - 128) * 64 + w * 16 + i;
                    const float* wr = Wo + (size_t)row * EDIM;
                    float s = 0.f;
                    #pragma unroll
                    for (int c2 = 0; c2 < 8; c2++)
                        s += bv[lane + 64 * c2] * wr[lane + 64 * c2];
                    #pragma unroll
                    for (int off = 32; off; off >>= 1) s += __shfl_down(s, off);
                    if (lane == 0) bob[row] = bo[row] + s;
                }
            } else if (blk == 136) {
                // ---- zero S (4096 f32) ----
                #pragma unroll
                for (int i = 0; i < 4; i++)
                    ((float4*)S)[i * 256 + tid] = (float4){0.f, 0.f, 0.f, 0.f};
            } else if (blk < 201) {
                // ---- WvT: 64x64 transpose tile, WvT[e][e'] = bf16(Wv[e'][e]) ----
                int wt = blk - 137;
                int r0 = (wt >> 3) * 64, c0 = (wt & 7) * 64;
                ushort_t (*tt)[65] = (ushort_t (*)[65])sm.t.tile;
                #pragma unroll
                for (int p = 0; p < 16; p++) {
                    int idx = p * 256 + tid, r = idx >> 6, c = idx & 63;
                    tt[c][r] = f2bf(Wv[(size_t)(r0 + r) * EDIM + c0 + c]);
                }
                __syncthreads();
                #pragma unroll
                for (int p = 0; p < 16; p++) {
                    int idx = p * 256 + tid, r = idx >> 6, c = idx & 63;
                    WvT[(size_t)(c0 + r) * EDIM + r0 + c] = tt[r][c];
                }
            } else {
                // ---- converts (value->Vb, Wo->Wob) + M zero, grid-stride ----
                for (size_t u = (size_t)(blk - 201) * 256 + tid; u < TOT_U;
                     u += (size_t)311 * 256) {
                    if (u < CVT_U) {
                        size_t i = u * 8;
                        const float* src; ushort_t* dst; size_t off;
                        if (i < CVT_N0) { src = value; dst = Vb;  off = i; }
                        else            { src = Wo;    dst = Wob; off = i - CVT_N0; }
                        float4 a = *(const float4*)(src + off);
                        float4 b = *(const float4*)(src + off + 4);
                        ushort4 o0, o1;
                        o0.x = f2bf(a.x); o0.y = f2bf(a.y);
                        o0.z = f2bf(a.z); o0.w = f2bf(a.w);
                        o1.x = f2bf(b.x); o1.y = f2bf(b.y);
                        o1.z = f2bf(b.z); o1.w = f2bf(b.w);
                        *(ushort4*)(dst + off)     = o0;
                        *(ushort4*)(dst + off + 4) = o1;
                    } else {
                        *(int4*)(M + (u - CVT_U) * 16) = (int4){0, 0, 0, 0};
                    }
                }
            }
        } else if (ph == 1) {
            if (blk < 64) {
                // ---- Wvo[n,e] = Wob[n,:].WvT[e,:] ----
                gemm64_dev<0>(Wob, WvT, Wvo, nullptr,
                              EDIM, EDIM, EDIM, EDIM,
                              (blk >> 3) * 64, (blk & 7) * 64,
                              sm.g.As[0], sm.g.Bs[0], tid);
            } else {
                // ---- sparse join: 448 blocks cover 512 (b,k) units ----
                for (int u = blk - 64; u < 512; u += 448) {
                    __syncthreads();      // protect table re-init vs prior probes
                    int b = u >> 7, k = u & 127;
                    const unsigned* kc = sigTk + (size_t)k * (NB * LK) + b * LK;
                    const unsigned* qc = sigTq + (size_t)k * (NB * LQ) + b * LQ;
                    uint4 kv = ((const uint4*)kc)[tid];
                    uint4 qv = ((const uint4*)qc)[tid];
                    #pragma unroll
                    for (int i = 0; i < 8; i++)
                        sm.j.keys[i * 256 + tid] = 0xFFFFFFFFu;
                    __syncthreads();
                    // insert: 4 interleaved CAS walks
                    unsigned vvv[4] = {kv.x, kv.y, kv.z, kv.w};
                    unsigned hh[4]; bool dn[4];
                    #pragma unroll
                    for (int e = 0; e < 4; e++) {
                        hh[e] = (vvv[e] * 2654435761u) >> 21; dn[e] = false;
                    }
                    int rem = 4;
                    while (rem) {
                        #pragma unroll
                        for (int e = 0; e < 4; e++) {
                            if (dn[e]) continue;
                            unsigned prev =
                                atomicCAS(&sm.j.keys[hh[e]], 0xFFFFFFFFu, vvv[e]);
                            if (prev == 0xFFFFFFFFu) {
                                sm.j.vals[hh[e]] = (ushort_t)(tid * 4 + e);
                                dn[e] = true; rem--;
                            } else hh[e] = (hh[e] + 1) & 2047;
                        }
                    }
                    __syncthreads();
                    // probe: 4 interleaved walks; fire-and-forget M atomics
                    uint8_t* Mb = M + ((size_t)b << 20);
                    unsigned qq[4] = {qv.x, qv.y, qv.z, qv.w};
                    #pragma unroll
                    for (int e = 0; e < 4; e++) {
                        hh[e] = (qq[e] * 2654435761u) >> 21; dn[e] = false;
                    }
                    rem = 4;
                    while (rem) {
                        unsigned kk[4];
                        #pragma unroll
                        for (int e = 0; e < 4; e++) kk[e] = sm.j.keys[hh[e]];
                        #pragma unroll
                        for (int e = 0; e < 4; e++) {
                            if (dn[e]) continue;
                            if (kk[e] == 0xFFFFFFFFu) { dn[e] = true; rem--; }
                            else {
                                if (kk[e] == qq[e]) {
                                    unsigned ix = ((unsigned)(tid * 4 + e) << 10)
                                                  + sm.j.vals[hh[e]];
                                    atomicAdd((unsigned*)(Mb + (ix & ~3u)),
                                              1u << ((ix & 3u) * 8));
                                }
                                hh[e] = (hh[e] + 1) & 2047;
                            }
                        }
                    }
                }
            }
        } else if (ph == 2) {
            // ---- W2c = Vb @ Wvo^T, 512 tiles, with column-sum S epilogue ----
            gemm64_dev<1>(Vb, Wvo, W2c, S,
                          EDIM, EDIM, EDIM, EDIM,
                          (blk >> 3) * 64, (blk & 7) * 64,
                          sm.g.As[0], sm.g.Bs[0], tid);
        } else {
            // ---- out rows: 8 per block ----
            float p0 = score_of(0);
            for (int it = 0; it < 8; it++) {
                int row = blk + 512 * it, b = row >> 10;
                const uint8_t* Mr = M + ((size_t)row << 10);
                float acc0 = 0.f, acc1 = 0.f, drs = 0.f;
                int n0 = tid * 2;
                for (int c = 0; c < 4; c++) {
                    if (tid == 0) sm.o.lcnt = 0;
                    __syncthreads();
                    uint8_t m = Mr[c * 256 + tid];
                    if (m) {
                        unsigned s = atomicAdd(&sm.o.lcnt, 1u);  // cap 256 exact
                        sm.o.lj[s] = c * 256 + tid;
                        sm.o.lp[s] = score_of((int)m) - p0;
                    }
                    __syncthreads();
                    unsigned cnt = sm.o.lcnt;
                    for (unsigned i = 0; i < cnt; i++) {
                        float w = sm.o.lp[i];
                        drs += w;                    // same order on all threads
                        const ushort_t* wr =
                            W2c + (((size_t)(b << 10) + sm.o.lj[i]) << 9);
                        unsigned pk = *(const unsigned*)(wr + n0);
                        acc0 += w * __builtin_bit_cast(float, pk << 16);
                        acc1 += w * __builtin_bit_cast(float, pk & 0xFFFF0000u);
                    }
                    __syncthreads();
                }
                float rs = 1024.0f * p0 + drs;
                float inv = 1.0f / rs;
                float2 sv = *(const float2*)(S + b * EDIM + n0);
                float2 bb = *(const float2*)(bob + n0);
                float2 o;
                o.x = (p0 * sv.x + acc0) * inv + bb.x;
                o.y = (p0 * sv.y + acc1) * inv + bb.y;
                *(float2*)(out + (size_t)row * EDIM + n0) = o;
            }
        }
        if (ph < phi) {
            __threadfence();
            cg::this_grid().sync();
        }
    }
}

// ---------------------------------------------------------------------------
extern "C" void kernel_launch(void* const* d_in, const int* in_sizes, int n_in,
                              void* d_out, int out_size, void* d_ws, size_t ws_size,
                              hipStream_t stream) {
    // inputs: 0 query 1 key 2 value 3 ts_q 4 ts_k 5 ha 6 hb 7 Wq 8 bq 9 Wk 10 bk
    //         11 Wv 12 bv 13 Wo 14 bo   (q/k projections are dead code)
    const float* value = (const float*)d_in[2];
    const int* tsq = (const int*)d_in[3];
    const int* tsk = (const int*)d_in[4];
    const int* ha  = (const int*)d_in[5];
    const int* hb  = (const int*)d_in[6];
    const float* Wv = (const float*)d_in[11];
    const float* bv = (const float*)d_in[12];
    const float* Wo = (const float*)d_in[13];
    const float* bo = (const float*)d_in[14];
    float* out = (float*)d_out;

    char* ws = (char*)d_ws;
    unsigned* sigTq = (unsigned*)(ws);                         // 2 MB [128][4096]
    unsigned* sigTk = (unsigned*)(ws + (2ull << 20));          // 2 MB [128][4096]
    uint8_t*  M     = (uint8_t*)(ws + (4ull << 20));           // 4 MB
    ushort_t* Vb    = (ushort_t*)(ws + (8ull << 20));          // 4 MB [4096 x 512]
    ushort_t* W2c   = (ushort_t*)(ws + (12ull << 20));         // 4 MB [4096 x 512]
    ushort_t* Wob   = (ushort_t*)(ws + (16ull << 20));         // 512 KB
    ushort_t* WvT   = (ushort_t*)(ws + (16ull << 20) + (512ull << 10)); // 512 KB
    ushort_t* Wvo   = (ushort_t*)(ws + (17ull << 20));         // 512 KB
    float* S        = (float*)(ws + (17ull << 20) + (512ull << 10));    // 16 KB
    float* bob      = (float*)(ws + (17ull << 20) + (528ull << 10));    // 2 KB

    int plo = 0, phi = 3;
    void* args[] = {
        (void*)&value, (void*)&Wv, (void*)&Wo, (void*)&bv, (void*)&bo,
        (void*)&tsq, (void*)&tsk, (void*)&ha, (void*)&hb,
        (void*)&sigTq, (void*)&sigTk, (void*)&M,
        (void*)&Vb, (void*)&Wob, (void*)&WvT, (void*)&Wvo,
        (void*)&W2c, (void*)&S, (void*)&bob, (void*)&out,
        (void*)&plo, (void*)&phi
    };
    hipError_t err = hipLaunchCooperativeKernel(
        (void*)fused_kernel, dim3(512), dim3(256), args, 0, stream);
    if (err != hipSuccess) {
        // fallback: 4 plain launches, one phase each (grid.sync never runs)
        for (int p = 0; p < 4; p++)
            fused_kernel<<<512, 256, 0, stream>>>(
                value, Wv, Wo, bv, bo, tsq, tsk, ha, hb,
                sigTq, sigTk, M, Vb, Wob, WvT, Wvo, W2c, S, bob, out, p, p);
    }
}

// Round 14
// 157.578 us; speedup vs baseline: 3.4664x; 3.4664x over previous
//
#include <hip/hip_runtime.h>
#include <hip/hip_bf16.h>
#include <stdint.h>

// Problem constants (fixed by setup_inputs)
#define PRIME 2147483647u
#define GAMMA 0.3f
#define K_HASH 128
#define S_SET 8
#define NB 4
#define LQ 1024
#define LK 1024
#define EDIM 512

typedef unsigned short ushort_t;
typedef __attribute__((ext_vector_type(8))) short short8;
typedef __attribute__((ext_vector_type(4))) float f32x4;

static __device__ __forceinline__ unsigned short f2bf(float f) {
    unsigned u = __builtin_bit_cast(unsigned, f);
    u += 0x7FFFu + ((u >> 16) & 1u);   // RNE (no NaN in this problem)
    return (unsigned short)(u >> 16);
}

// async global->LDS, 16B per lane; LDS dst must be lane-contiguous.
static __device__ __forceinline__ void glds16(const void* g, void* l) {
    __builtin_amdgcn_global_load_lds(
        (const __attribute__((address_space(1))) unsigned int*)g,
        (__attribute__((address_space(3))) unsigned int*)l, 16, 0, 0);
}

#define SWZ(r) ((((r) >> 2) & 3) ^ ((r) & 3))

// score(m) = exp(exp(-GAMMA * 2S * (K-m)/(K+m))), m = matched hash slots
static __device__ __forceinline__ float score_of(int m) {
    float r = (float)(K_HASH - m) / (float)(K_HASH + m);
    return expf(expf(-GAMMA * (2.0f * S_SET) * r));
}

// ---------------------------------------------------------------------------
// 64x64-tile bf16 BT-GEMM device fn: C=A@B^T, f32 accum, 4 waves x 32x32,
// glds width-16, XOR-swizzled LDS, double-buffered.
// SEPI=1: atomicAdd per-column f32 sums into Sacc[b][n] (b = m0>>10).
// ---------------------------------------------------------------------------
template<int SEPI>
static __device__ void gemm64_dev(
        const ushort_t* __restrict__ A, const ushort_t* __restrict__ B,
        ushort_t* __restrict__ C, float* __restrict__ Sacc,
        int lda, int ldb, int ldc, int Kd, int m0, int n0,
        ushort_t* AsBase, ushort_t* BsBase, int tid) {
    ushort_t (*As)[64 * 32] = (ushort_t (*)[64 * 32])AsBase;
    ushort_t (*Bs)[64 * 32] = (ushort_t (*)[64 * 32])BsBase;
    int w = tid >> 6, lane = tid & 63;
    int wm = (w & 1) * 32, wn = (w >> 1) * 32;
    int mrow = lane & 15, kg = lane >> 4;

    int r = tid >> 2, c = (tid & 3) ^ SWZ(r);
    const ushort_t* pa = A + (size_t)(m0 + r) * lda + c * 8;
    const ushort_t* pb = B + (size_t)(n0 + r) * ldb + c * 8;

    int aoff[2], boff[2];
    #pragma unroll
    for (int s = 0; s < 2; s++) {
        int Ra = wm + s * 16 + mrow;
        aoff[s] = Ra * 32 + (kg ^ SWZ(Ra)) * 8;
        int Rb = wn + s * 16 + mrow;
        boff[s] = Rb * 32 + (kg ^ SWZ(Rb)) * 8;
    }

    f32x4 acc[2][2] = {};
    int nK = Kd >> 5;
    glds16(pa, &As[0][tid * 8]);
    glds16(pb, &Bs[0][tid * 8]);
    for (int i = 0; i < nK; i++) {
        __syncthreads();
        int cur = i & 1, nxt = cur ^ 1;
        if (i + 1 < nK) {
            int k0 = (i + 1) << 5;
            glds16(pa + k0, &As[nxt][tid * 8]);
            glds16(pb + k0, &Bs[nxt][tid * 8]);
        }
        short8 af[2], bh[2];
        #pragma unroll
        for (int s = 0; s < 2; s++) {
            af[s] = *(const short8*)&As[cur][aoff[s]];
            bh[s] = *(const short8*)&Bs[cur][boff[s]];
        }
        #pragma unroll
        for (int ii = 0; ii < 2; ii++)
            #pragma unroll
            for (int jj = 0; jj < 2; jj++)
                acc[ii][jj] = __builtin_amdgcn_mfma_f32_16x16x32_bf16(
                                  af[ii], bh[jj], acc[ii][jj], 0, 0, 0);
    }

    int col = lane & 15, rbase = (lane >> 4) * 4;
    #pragma unroll
    for (int ii = 0; ii < 2; ii++) {
        #pragma unroll
        for (int jj = 0; jj < 2; jj++) {
            #pragma unroll
            for (int rr = 0; rr < 4; rr++) {
                int gm = m0 + wm + ii * 16 + rbase + rr;
                int gn = n0 + wn + jj * 16 + col;
                C[(size_t)gm * ldc + gn] = f2bf(acc[ii][jj][rr]);
            }
        }
    }
    if (SEPI) {
        // column sums of this wave's 32 rows -> S[b][n], b = m0>>10
        #pragma unroll
        for (int jj = 0; jj < 2; jj++) {
            float s = 0.f;
            #pragma unroll
            for (int ii = 0; ii < 2; ii++)
                #pragma unroll
                for (int rr = 0; rr < 4; rr++) s += acc[ii][jj][rr];
            s += __shfl_xor(s, 16);          // reduce across the 4 row-groups
            s += __shfl_xor(s, 32);
            if ((lane >> 4) == 0)
                atomicAdd(&Sacc[(m0 >> 10) * EDIM + n0 + wn + jj * 16 + col], s);
        }
    }
}

// ---------------------------------------------------------------------------
// 1) prep (HEAVY roles first -- R9 had sigT at the grid tail = straggler):
//    sigT[k][4096] (u32, LDS transpose) | WvT = Wv^T (bf16 tiles) |
//    bob = bo + bv@Wo^T (wave-per-row) | zero S |
//    value->Vb, Wo->Wob (bf16) | zero M.
// ---------------------------------------------------------------------------
#define SIGT_BLOCKS 128    // 8192 rows / 64 rows per block
#define WVT_BLOCKS 64      // 8x8 64x64 transpose tiles
#define BOB_BLOCKS 8
#define SZ_BLOCKS 1
#define CVT_N0 (NB * LK * EDIM)
#define CVT_N1 (EDIM * EDIM)
#define CVT_BLOCKS ((CVT_N0 + CVT_N1) / (256 * 8))   // 1152
#define MZ_BLOCKS 1024     // 4 MB M / 4 KB
#define PREP_GRID (SIGT_BLOCKS + WVT_BLOCKS + BOB_BLOCKS + SZ_BLOCKS + CVT_BLOCKS + MZ_BLOCKS)

__global__ __launch_bounds__(256) void prep_kernel(
        const float* __restrict__ value, const float* __restrict__ Wv,
        const float* __restrict__ Wo, const float* __restrict__ bv,
        const float* __restrict__ bo,
        ushort_t* __restrict__ Vb, ushort_t* __restrict__ Wob,
        ushort_t* __restrict__ WvT,
        const int* __restrict__ ts_q, const int* __restrict__ ts_k,
        const int* __restrict__ ha, const int* __restrict__ hb,
        unsigned* __restrict__ sigTq, unsigned* __restrict__ sigTk,
        uint8_t* __restrict__ M, float* __restrict__ S,
        float* __restrict__ bob) {
    __shared__ unsigned tile[128 * 65];   // sigT transpose / WvT (ushort view)
    __shared__ int ids_s[64 * S_SET];
    int blk = blockIdx.x, tid = threadIdx.x;
    if (blk < SIGT_BLOCKS) {
        // ---- sigT: 64 rows x all 128 k, written column-major ----
        int r0 = blk * 64;                // global row 0..8191 (q then k)
        const int* ts = (r0 < NB * LQ) ? ts_q : ts_k;
        unsigned* sigT = (r0 < NB * LQ) ? sigTq : sigTk;
        int base = r0 & (NB * LQ - 1);
        ((int2*)ids_s)[tid] = ((const int2*)(ts + (size_t)base * S_SET))[tid];
        __syncthreads();
        int kt = tid & 127, rt = tid >> 7;
        unsigned long long a  = (unsigned)ha[kt];
        unsigned long long bb = (unsigned)hb[kt];
        for (int r = rt; r < 64; r += 2) {
            unsigned mn = 0xFFFFFFFFu;
            #pragma unroll
            for (int s = 0; s < S_SET; s++) {
                unsigned long long x =
                    a * (unsigned long long)(unsigned)ids_s[r * S_SET + s] + bb;
                x = (x & PRIME) + (x >> 31);  // 2^31 == 1 (mod 2^31-1)
                x = (x & PRIME) + (x >> 31);
                unsigned rr = (unsigned)x;
                if (rr >= PRIME) rr -= PRIME;
                mn = (rr < mn) ? rr : mn;
            }
            tile[kt * 65 + r] = mn;
        }
        __syncthreads();
        #pragma unroll
        for (int ch = 0; ch < 32; ch++) {
            int idx = ch * 256 + tid;
            int k = idx >> 6, r = idx & 63;
            sigT[(size_t)k * (NB * LQ) + base + r] = tile[k * 65 + r];
        }
        return;
    }
    if (blk < SIGT_BLOCKS + WVT_BLOCKS) {
        // ---- WvT: 64x64 transpose tiles, WvT[e][e'] = bf16(Wv[e'][e]) ----
        int wt = blk - SIGT_BLOCKS;
        int r0 = (wt >> 3) * 64, c0 = (wt & 7) * 64;
        ushort_t (*tt)[65] = (ushort_t (*)[65])tile;
        #pragma unroll
        for (int p = 0; p < 16; p++) {
            int idx = p * 256 + tid, r = idx >> 6, c = idx & 63;
            tt[c][r] = f2bf(Wv[(size_t)(r0 + r) * EDIM + c0 + c]);
        }
        __syncthreads();
        #pragma unroll
        for (int p = 0; p < 16; p++) {
            int idx = p * 256 + tid, r = idx >> 6, c = idx & 63;
            WvT[(size_t)(c0 + r) * EDIM + r0 + c] = tt[r][c];
        }
        return;
    }
    if (blk < SIGT_BLOCKS + WVT_BLOCKS + BOB_BLOCKS) {
        // ---- bob = bo + bv@Wo^T: wave-per-row coalesced reduce ----
        int bb2 = blk - SIGT_BLOCKS - WVT_BLOCKS;
        int w = tid >> 6, lane = tid & 63;
        #pragma unroll
        for (int i = 0; i < 16; i++) {
            int row = bb2 * 64 + w * 16 + i;
            const float* wr = Wo + (size_t)row * EDIM;
            float s = 0.f;
            #pragma unroll
            for (int c2 = 0; c2 < 8; c2++)
                s += bv[lane + 64 * c2] * wr[lane + 64 * c2];
            #pragma unroll
            for (int off = 32; off; off >>= 1) s += __shfl_down(s, off);
            if (lane == 0) bob[row] = bo[row] + s;
        }
        return;
    }
    if (blk < SIGT_BLOCKS + WVT_BLOCKS + BOB_BLOCKS + SZ_BLOCKS) {
        // ---- zero S (4096 f32) ----
        ((float2*)S)[tid] = (float2){0.f, 0.f};
        ((float2*)S)[256 + tid] = (float2){0.f, 0.f};
        ((float2*)S)[512 + tid] = (float2){0.f, 0.f};
        ((float2*)S)[768 + tid] = (float2){0.f, 0.f};
        return;
    }
    if (blk < SIGT_BLOCKS + WVT_BLOCKS + BOB_BLOCKS + SZ_BLOCKS + CVT_BLOCKS) {
        // ---- convert: value->Vb, Wo->Wob ----
        size_t i = ((size_t)(blk - SIGT_BLOCKS - WVT_BLOCKS - BOB_BLOCKS - SZ_BLOCKS)
                    * 256 + tid) * 8;
        const float* src; ushort_t* dst; size_t off;
        if (i < CVT_N0) { src = value; dst = Vb;  off = i; }
        else            { src = Wo;    dst = Wob; off = i - CVT_N0; }
        float4 a = *(const float4*)(src + off);
        float4 b = *(const float4*)(src + off + 4);
        ushort4 o0, o1;
        o0.x = f2bf(a.x); o0.y = f2bf(a.y); o0.z = f2bf(a.z); o0.w = f2bf(a.w);
        o1.x = f2bf(b.x); o1.y = f2bf(b.y); o1.z = f2bf(b.z); o1.w = f2bf(b.w);
        *(ushort4*)(dst + off)     = o0;
        *(ushort4*)(dst + off + 4) = o1;
        return;
    }
    // ---- zero M ----
    size_t off = ((size_t)(blk - SIGT_BLOCKS - WVT_BLOCKS - BOB_BLOCKS - SZ_BLOCKS
                           - CVT_BLOCKS) * 256 + tid) * 16;
    *(int4*)(M + off) = (int4){0, 0, 0, 0};
}

// ---------------------------------------------------------------------------
// 2) joing1: Wvo = Wob@WvT^T (64 tiles, blk<64)  ||  sparse equality join
//    (512 blocks): one (b,k) per block, two contiguous 4 KB sigT columns,
//    2048-slot LDS table (dups kept -> exact multiplicity), 4-way interleaved
//    hash walks, fire-and-forget byte atomicAdds into M.
// ---------------------------------------------------------------------------
union JSmem {
    struct { unsigned keys[2048]; ushort_t vals[2048]; } j;   // 12 KB
    struct { ushort_t As[2][64 * 32]; ushort_t Bs[2][64 * 32]; } g; // 16 KB
};

__global__ __launch_bounds__(256) void joing1_kernel(
        const unsigned* __restrict__ sigTq, const unsigned* __restrict__ sigTk,
        uint8_t* __restrict__ M,
        const ushort_t* __restrict__ Wob, const ushort_t* __restrict__ WvT,
        ushort_t* __restrict__ Wvo) {
    __shared__ JSmem sm;
    int blk = blockIdx.x, tid = threadIdx.x;
    if (blk < 64) {                       // ---- Wvo[n,e] = Wob[n,:].WvT[e,:] ----
        gemm64_dev<0>(Wob, WvT, Wvo, nullptr,
                      EDIM, EDIM, EDIM, EDIM,
                      (blk >> 3) * 64, (blk & 7) * 64,
                      sm.g.As[0], sm.g.Bs[0], tid);
        return;
    }
    // ---- join block: batch b, hash column k ----
    int jt = blk - 64, b = jt >> 7, k = jt & 127;
    const unsigned* kc = sigTk + (size_t)k * (NB * LK) + b * LK;
    const unsigned* qc = sigTq + (size_t)k * (NB * LQ) + b * LQ;
    uint4 kv = ((const uint4*)kc)[tid];   // j = tid*4 .. tid*4+3
    uint4 qv = ((const uint4*)qc)[tid];
    #pragma unroll
    for (int i = 0; i < 8; i++) sm.j.keys[i * 256 + tid] = 0xFFFFFFFFu;
    __syncthreads();
    // insert: 4 interleaved walks (independent CAS chains hide LDS latency)
    unsigned vvv[4] = {kv.x, kv.y, kv.z, kv.w};
    unsigned hh[4]; bool dn[4];
    #pragma unroll
    for (int e = 0; e < 4; e++) { hh[e] = (vvv[e] * 2654435761u) >> 21; dn[e] = false; }
    int rem = 4;
    while (rem) {
        #pragma unroll
        for (int e = 0; e < 4; e++) {
            if (dn[e]) continue;
            unsigned prev = atomicCAS(&sm.j.keys[hh[e]], 0xFFFFFFFFu, vvv[e]);
            if (prev == 0xFFFFFFFFu) {
                sm.j.vals[hh[e]] = (ushort_t)(tid * 4 + e);
                dn[e] = true; rem--;
            } else hh[e] = (hh[e] + 1) & 2047;
        }
    }
    __syncthreads();
    // probe: 4 interleaved walks; M atomicAdd result unused -> no stall
    uint8_t* Mb = M + ((size_t)b << 20);
    unsigned qq[4] = {qv.x, qv.y, qv.z, qv.w};
    #pragma unroll
    for (int e = 0; e < 4; e++) { hh[e] = (qq[e] * 2654435761u) >> 21; dn[e] = false; }
    rem = 4;
    while (rem) {
        unsigned kk[4];
        #pragma unroll
        for (int e = 0; e < 4; e++) kk[e] = sm.j.keys[hh[e]];  // 4 loads, 1 wait
        #pragma unroll
        for (int e = 0; e < 4; e++) {
            if (dn[e]) continue;
            if (kk[e] == 0xFFFFFFFFu) { dn[e] = true; rem--; }
            else {
                if (kk[e] == qq[e]) {
                    unsigned ix = ((unsigned)(tid * 4 + e) << 10) + sm.j.vals[hh[e]];
                    atomicAdd((unsigned*)(Mb + (ix & ~3u)), 1u << ((ix & 3u) * 8));
                }
                hh[e] = (hh[e] + 1) & 2047;
            }
        }
    }
}

// ---------------------------------------------------------------------------
// 3) g2: W2c = Vb @ Wvo^T (512 tiles) with in-epilogue column-sum S (no
//    separate S role -> no straggler tail).
// ---------------------------------------------------------------------------
__global__ __launch_bounds__(256) void g2_kernel(
        const ushort_t* __restrict__ Vb, const ushort_t* __restrict__ Wvo,
        ushort_t* __restrict__ W2c, float* __restrict__ S) {
    __shared__ ushort_t As[2][64 * 32], Bs[2][64 * 32];
    int blk = blockIdx.x;
    gemm64_dev<1>(Vb, Wvo, W2c, S,
                  EDIM, EDIM, EDIM, EDIM,
                  (blk >> 3) * 64, (blk & 7) * 64,
                  As[0], Bs[0], threadIdx.x);
}

// ---------------------------------------------------------------------------
// 4) outk: one block per (b,q) row. Scans its own M row (1 KB, 4 chunks of
//    256 so LDS list capacity is exact), builds ΔP list, computes rs in-block
//    (deterministic), then out = (p0*S + Σ ΔP*W2c[j,:])/rs + bob.
//    No P matrix, no rs array, no global atomics.
// ---------------------------------------------------------------------------
__global__ __launch_bounds__(256) void outk_kernel(
        const uint8_t* __restrict__ M, const ushort_t* __restrict__ W2c,
        const float* __restrict__ S, const float* __restrict__ bob,
        float* __restrict__ out) {
    __shared__ unsigned lj[256];
    __shared__ float lp[256];
    __shared__ unsigned lcnt;
    int row = blockIdx.x, tid = threadIdx.x, b = row >> 10;
    const uint8_t* Mr = M + ((size_t)row << 10);
    float p0 = score_of(0);
    float acc0 = 0.f, acc1 = 0.f, drs = 0.f;
    int n0 = tid * 2;
    for (int c = 0; c < 4; c++) {
        if (tid == 0) lcnt = 0;
        __syncthreads();
        uint8_t m = Mr[c * 256 + tid];
        if (m) {
            unsigned s = atomicAdd(&lcnt, 1u);   // capacity 256 = exact bound
            lj[s] = c * 256 + tid;
            lp[s] = score_of((int)m) - p0;
        }
        __syncthreads();
        unsigned cnt = lcnt;
        for (unsigned i = 0; i < cnt; i++) {
            float w = lp[i];
            drs += w;                            // same order on all threads
            const ushort_t* wr = W2c + (((size_t)(b << 10) + lj[i]) << 9);
            unsigned pk = *(const unsigned*)(wr + n0);
            acc0 += w * __builtin_bit_cast(float, pk << 16);
            acc1 += w * __builtin_bit_cast(float, pk & 0xFFFF0000u);
        }
        __syncthreads();
    }
    float rs = 1024.0f * p0 + drs;
    float inv = 1.0f / rs;
    float2 sv = *(const float2*)(S + b * EDIM + n0);
    float2 bb = *(const float2*)(bob + n0);
    float2 o;
    o.x = (p0 * sv.x + acc0) * inv + bb.x;
    o.y = (p0 * sv.y + acc1) * inv + bb.y;
    *(float2*)(out + (size_t)row * EDIM + n0) = o;
}

// ---------------------------------------------------------------------------
extern "C" void kernel_launch(void* const* d_in, const int* in_sizes, int n_in,
                              void* d_out, int out_size, void* d_ws, size_t ws_size,
                              hipStream_t stream) {
    // inputs: 0 query 1 key 2 value 3 ts_q 4 ts_k 5 ha 6 hb 7 Wq 8 bq 9 Wk 10 bk
    //         11 Wv 12 bv 13 Wo 14 bo   (q/k projections are dead code)
    const float* value = (const float*)d_in[2];
    const int* tsq = (const int*)d_in[3];
    const int* tsk = (const int*)d_in[4];
    const int* ha  = (const int*)d_in[5];
    const int* hb  = (const int*)d_in[6];
    const float* Wv = (const float*)d_in[11];
    const float* bv = (const float*)d_in[12];
    const float* Wo = (const float*)d_in[13];
    const float* bo = (const float*)d_in[14];
    float* out = (float*)d_out;

    char* ws = (char*)d_ws;
    unsigned* sigTq = (unsigned*)(ws);                         // 2 MB [128][4096]
    unsigned* sigTk = (unsigned*)(ws + (2ull << 20));          // 2 MB [128][4096]
    uint8_t*  M     = (uint8_t*)(ws + (4ull << 20));           // 4 MB
    ushort_t* Vb    = (ushort_t*)(ws + (8ull << 20));          // 4 MB [4096 x 512]
    ushort_t* W2c   = (ushort_t*)(ws + (12ull << 20));         // 4 MB [4096 x 512]
    ushort_t* Wob   = (ushort_t*)(ws + (16ull << 20));         // 512 KB
    ushort_t* WvT   = (ushort_t*)(ws + (16ull << 20) + (512ull << 10)); // 512 KB
    ushort_t* Wvo   = (ushort_t*)(ws + (17ull << 20));         // 512 KB
    float* S        = (float*)(ws + (17ull << 20) + (512ull << 10));    // 16 KB
    float* bob      = (float*)(ws + (17ull << 20) + (528ull << 10));    // 2 KB

    // 1) sigT + WvT + bob + S zero + converts + M zero (heavy roles first)
    prep_kernel<<<PREP_GRID, 256, 0, stream>>>(
        value, Wv, Wo, bv, bo, Vb, Wob, WvT,
        tsq, tsk, ha, hb, sigTq, sigTk, M, S, bob);

    // 2) Wvo GEMM (64) || sparse join (512)
    joing1_kernel<<<576, 256, 0, stream>>>(
        sigTq, sigTk, M, Wob, WvT, Wvo);

    // 3) W2c = Vb @ Wvo^T (512 tiles) with column-sum S epilogue
    g2_kernel<<<512, 256, 0, stream>>>(Vb, Wvo, W2c, S);

    // 4) out[b,q,:] = (p0*S[b,:] + Σ ΔP*W2c[j,:]) / rs + bob
    outk_kernel<<<NB * LQ, 256, 0, stream>>>(M, W2c, S, bob, out);
}